// Round 17
// baseline (632.554 us; speedup 1.0000x reference)
//
#include <hip/hip_runtime.h>
#include <hip/hip_bf16.h>

// C[32768,2304] = A[32768,768] * W^T + b ; outputs q,k,v [32768,768] fp32 each.
#define M_TOT 32768
#define K_TOT 768
#define N_TOT 2304
#define H     768
#define BM 256
#define BN 256
#define BK 64
#define NBN 9                    // N_TOT/BN
#define NBM 128                  // M_TOT/BM
#define NBLK (NBM*NBN)           // 1152, %8==0 -> XCD swizzle bijective
#define NKT  (K_TOT/BK)          // 12
#define GRAN 98304               // granule = 128 rows x 768 k (elems)
#define OUT_PER 25165824         // M_TOT*H

typedef __attribute__((ext_vector_type(8))) short bf16x8;
typedef __attribute__((ext_vector_type(8))) unsigned short u16x8;
typedef __attribute__((ext_vector_type(4))) float f32x4;

__device__ __forceinline__ void gld_lds16(const void* g, void* l) {
    __builtin_amdgcn_global_load_lds(
        (const __attribute__((address_space(1))) unsigned int*)g,
        (__attribute__((address_space(3))) unsigned int*)l,
        16, 0, 0);
}

__device__ __forceinline__ unsigned short f2bf_rne(float f) {
    unsigned u = __builtin_bit_cast(unsigned, f);
    unsigned r = (u + 0x7FFFu + ((u >> 16) & 1u)) >> 16;
    return (unsigned short)r;
}

// ---------------------------------------------------------------------------
// Pass 1 (R12-proven, ~25us): fp32 -> bf16 convert + pack into tiled layout
// pk[gran][kt][kb8][row128][8]; granule = 128 rows x 768 k.
// ---------------------------------------------------------------------------
#define A_TILES 3072             // 256 m-granules x 12 k-tiles
#define W_TILES 216              // 18 row-granules x 12 k-tiles
#define LDSW 68

__global__ void convert_pack(const float* __restrict__ A,
                             const float* __restrict__ wq, const float* __restrict__ wk,
                             const float* __restrict__ wv,
                             const float* __restrict__ bq, const float* __restrict__ bk,
                             const float* __restrict__ bv,
                             unsigned short* __restrict__ A_pk,
                             unsigned short* __restrict__ W_pk,
                             float* __restrict__ biasb) {
    __shared__ float lds_f[128 * LDSW];

    const int tid = threadIdx.x;
    const int t   = blockIdx.x;

    int gt = t * 256 + tid;
    if (gt < 2304) {
        biasb[gt] = (gt < 768) ? bq[gt] : (gt < 1536) ? bk[gt - 768] : bv[gt - 1536];
    }

    const float* src;
    unsigned short* dst;
    if (t < A_TILES) {
        const int mt = t / 12, kt = t - mt * 12;
        src = A + (size_t)mt * 128 * K_TOT + kt * 64;
        dst = A_pk + (size_t)t * 8192;
    } else {
        const int t2 = t - A_TILES;
        const int nt = t2 / 12, kt = t2 - nt * 12;
        const int which = nt / 6;
        const int row0  = (nt - which * 6) * 128;
        const float* w = (which == 0) ? wq : (which == 1) ? wk : wv;
        src = w + (size_t)row0 * K_TOT + kt * 64;
        dst = W_pk + (size_t)t2 * 8192;
    }

    #pragma unroll
    for (int j = 0; j < 8; ++j) {
        int f = j * 256 + tid;
        int row = f >> 4, c4 = f & 15;
        float4 v = *reinterpret_cast<const float4*>(src + (size_t)row * K_TOT + c4 * 4);
        *reinterpret_cast<float4*>(&lds_f[row * LDSW + c4 * 4]) = v;
    }
    __syncthreads();

    #pragma unroll
    for (int j = 0; j < 4; ++j) {
        int c = j * 256 + tid;
        int kb = c >> 7, row = c & 127;
        const float* p = &lds_f[row * LDSW + kb * 8];
        u16x8 o;
        #pragma unroll
        for (int e = 0; e < 8; ++e) o[e] = f2bf_rne(p[e]);
        *reinterpret_cast<u16x8*>(dst + (size_t)c * 8) = o;
    }
}

// ---------------------------------------------------------------------------
// Pass 2: 256x256 scale-up of the PROVEN R12 structure (same 2-barrier
// compiler-scheduled loop, packed conflict-free LDS, gld_lds staging,
// nt-store epilogue). 512 thr = 8 waves (2M x 4N), wave tile 128x64,
// acc[8][4]. Why: halves L3 staging traffic (A re-read 9x not 18x) and
// doubles MFMA per barrier-drain (64 vs 32 per wave).
// LDS 64 KB single-buffered -> 2 blocks/CU (16 waves/CU, same as R12).
// __launch_bounds__(512,4): VGPR cap 512 -> no spill (R13 lesson).
// ---------------------------------------------------------------------------
__global__ __launch_bounds__(512, 4) void qkv_gemm(
        const unsigned short* __restrict__ A_pk,
        const unsigned short* __restrict__ W_pk,
        const float* __restrict__ bias,
        float* __restrict__ out) {

    // main loop: sA 32KB (2 granules) + sB 32KB; epilogue overlays 32x260 f32.
    __shared__ __align__(16) unsigned char smem[65536];
    unsigned short* sA = (unsigned short*)smem;
    unsigned short* sB = (unsigned short*)(smem + 32768);
    float* sC = (float*)smem;

    const int tid  = threadIdx.x;
    const int lane = tid & 63;
    const int l15  = lane & 15;
    const int kq   = lane >> 4;      // 0..3
    const int wid  = tid >> 6;       // 0..7
    const int wm   = wid >> 2;       // 0..1 : rows wm*128..+127
    const int wn   = wid & 3;        // 0..3 : cols wn*64..+63

    int bid = (int)blockIdx.x;
    bid = (bid & 7) * (NBLK / 8) + (bid >> 3);     // XCD-aware (bijective)
    const int bm = bid / NBN;
    const int bn = bid - bm * NBN;
    const int m0 = bm * BM;
    const int n0 = bn * BN;

    f32x4 acc[8][4];
    #pragma unroll
    for (int i = 0; i < 8; ++i)
        #pragma unroll
        for (int j = 0; j < 4; ++j)
            acc[i][j] = (f32x4){0.f, 0.f, 0.f, 0.f};

    const unsigned short* aG0 = A_pk + (size_t)(2 * bm) * GRAN;
    const unsigned short* aG1 = aG0 + GRAN;
    const unsigned short* bG0 = W_pk + (size_t)(2 * bn) * GRAN;
    const unsigned short* bG1 = bG0 + GRAN;

    // fragment read byte-offsets in packed granules [kb8][row128][8]:
    //   af[mi][kk] = aOff + kk*8192 + mi*256 ; bf[nj][kk] = bOff + kk*8192 + nj*256
    const int aOff = wm * 16384 + kq * 2048 + l15 * 16;
    const int bOff = (wn >> 1) * 16384 + kq * 2048 + ((wn & 1) * 64 + l15) * 16;

    for (int kt = 0; kt < NKT; ++kt) {
        if (kt) __syncthreads();
        {
            const size_t ko = (size_t)kt * 8192;
            gld_lds16(aG0 + ko + tid * 8,        &sA[tid * 8]);
            gld_lds16(aG0 + ko + 4096 + tid * 8, &sA[4096 + tid * 8]);
            gld_lds16(aG1 + ko + tid * 8,        &sA[8192 + tid * 8]);
            gld_lds16(aG1 + ko + 4096 + tid * 8, &sA[12288 + tid * 8]);
            gld_lds16(bG0 + ko + tid * 8,        &sB[tid * 8]);
            gld_lds16(bG0 + ko + 4096 + tid * 8, &sB[4096 + tid * 8]);
            gld_lds16(bG1 + ko + tid * 8,        &sB[8192 + tid * 8]);
            gld_lds16(bG1 + ko + 4096 + tid * 8, &sB[12288 + tid * 8]);
        }
        __syncthreads();

        #pragma unroll
        for (int kk = 0; kk < 2; ++kk) {
            bf16x8 af[8], bf[4];
            #pragma unroll
            for (int mi = 0; mi < 8; ++mi)
                af[mi] = *reinterpret_cast<const bf16x8*>(
                    (const char*)sA + aOff + kk * 8192 + mi * 256);
            #pragma unroll
            for (int nj = 0; nj < 4; ++nj)
                bf[nj] = *reinterpret_cast<const bf16x8*>(
                    (const char*)sB + bOff + kk * 8192 + nj * 256);
            #pragma unroll
            for (int mi = 0; mi < 8; ++mi)
                #pragma unroll
                for (int nj = 0; nj < 4; ++nj)
                    // swapped operands: lane's 4 acc regs = 4 consecutive n
                    acc[mi][nj] = __builtin_amdgcn_mfma_f32_16x16x32_bf16(
                        bf[nj], af[mi], acc[mi][nj], 0, 0, 0);
        }
    }

    // ---- epilogue: 8 chunks of 32 tile-rows; chunk c owned by waves with
    // wm == c>>2 (i-stripes (c&3)*2, +1). LDS stage 32x260 f32, then
    // coalesced nt stores: 64 lanes cover one 1KB row (16B/lane).
    const int which = n0 / H;          // 768 = 3*256: tile within one output
    const int c0    = n0 - which * H;
    float* outB = out + (size_t)which * OUT_PER + (size_t)m0 * H + c0;

    #pragma unroll
    for (int c = 0; c < 8; ++c) {
        __syncthreads();   // LDS free (main-loop / prev-chunk reads done)
        if (wm == (c >> 2)) {
            #pragma unroll
            for (int ip = 0; ip < 2; ++ip) {
                const int i    = (c & 3) * 2 + ip;
                const int lrow = ip * 16 + l15;          // 0..31
                #pragma unroll
                for (int j = 0; j < 4; ++j) {
                    const int col = wn * 64 + j * 16 + kq * 4;
                    const float4 bv4 = *reinterpret_cast<const float4*>(&bias[n0 + col]);
                    f32x4 o;
                    o[0] = acc[i][j][0] + bv4.x;
                    o[1] = acc[i][j][1] + bv4.y;
                    o[2] = acc[i][j][2] + bv4.z;
                    o[3] = acc[i][j][3] + bv4.w;
                    *reinterpret_cast<f32x4*>(&sC[lrow * 260 + col]) = o;
                }
            }
        }
        __syncthreads();
        #pragma unroll
        for (int v = 0; v < 4; ++v) {
            const int flat = v * 512 + tid;    // 0..2047
            const int row  = flat >> 6;        // 0..31
            const int ch   = flat & 63;        // 16B chunk in 1KB row
            f32x4 o = *reinterpret_cast<const f32x4*>(&sC[row * 260 + ch * 4]);
            const int grow = c * 32 + row;
            __builtin_nontemporal_store(o,
                reinterpret_cast<f32x4*>(&outB[(size_t)grow * H + ch * 4]));
        }
    }
}

extern "C" void kernel_launch(void* const* d_in, const int* in_sizes, int n_in,
                              void* d_out, int out_size, void* d_ws, size_t ws_size,
                              hipStream_t stream) {
    const float* hs = (const float*)d_in[0];
    const float* wq = (const float*)d_in[1];
    const float* bq = (const float*)d_in[2];
    const float* wk = (const float*)d_in[3];
    const float* bk = (const float*)d_in[4];
    const float* wv = (const float*)d_in[5];
    const float* bv = (const float*)d_in[6];

    unsigned short* A_pk = (unsigned short*)d_ws;                 // 50,331,648 B
    unsigned short* W_pk = A_pk + (size_t)A_TILES * 8192;         //  3,538,944 B
    float* biasb         = (float*)(W_pk + (size_t)W_TILES * 8192);

    hipLaunchKernelGGL(convert_pack, dim3(A_TILES + W_TILES), dim3(256), 0, stream,
                       hs, wq, wk, wv, bq, bk, bv, A_pk, W_pk, biasb);

    hipLaunchKernelGGL(qkv_gemm, dim3(NBLK), dim3(512), 0, stream,
                       A_pk, W_pk, biasb, (float*)d_out);
}

// Round 18
// 157.972 us; speedup vs baseline: 4.0042x; 4.0042x over previous
//
#include <hip/hip_runtime.h>
#include <hip/hip_bf16.h>

// C[32768,2304] = A[32768,768] * W^T + b ; outputs q,k,v [32768,768] fp32 each.
#define M_TOT 32768
#define K_TOT 768
#define N_TOT 2304
#define H     768
#define BM 128
#define BN 128
#define BK 64
#define NBN 18                   // N_TOT/BN
#define NBM 256                  // M_TOT/BM
#define NBLK (NBM*NBN)           // 4608, %8==0 -> XCD swizzle bijective
#define NKT  (K_TOT/BK)          // 12
#define TILE_ELEMS 8192          // 128 rows x 64 k
#define OUT_PER 25165824         // M_TOT*H

typedef __attribute__((ext_vector_type(8))) short bf16x8;
typedef __attribute__((ext_vector_type(8))) unsigned short u16x8;
typedef __attribute__((ext_vector_type(4))) float f32x4;

__device__ __forceinline__ void gld_lds16(const void* g, void* l) {
    __builtin_amdgcn_global_load_lds(
        (const __attribute__((address_space(1))) unsigned int*)g,
        (__attribute__((address_space(3))) unsigned int*)l,
        16, 0, 0);
}

__device__ __forceinline__ unsigned short f2bf_rne(float f) {
    unsigned u = __builtin_bit_cast(unsigned, f);
    unsigned r = (u + 0x7FFFu + ((u >> 16) & 1u)) >> 16;
    return (unsigned short)r;
}

// ---------------------------------------------------------------------------
// Pass 1 (R12-proven, ~25us): fp32 -> bf16 convert + pack into tiled layout
// pk[gran][kt][kb8][row128][8]; granule = 128 rows x 768 k. Plain caching
// loads/stores (R16 showed nt fp32 loads are neutral-to-negative).
// ---------------------------------------------------------------------------
#define A_TILES 3072             // 256 m-granules x 12 k-tiles
#define W_TILES 216              // 18 row-granules x 12 k-tiles
#define LDSW 68

__global__ void convert_pack(const float* __restrict__ A,
                             const float* __restrict__ wq, const float* __restrict__ wk,
                             const float* __restrict__ wv,
                             const float* __restrict__ bq, const float* __restrict__ bk,
                             const float* __restrict__ bv,
                             unsigned short* __restrict__ A_pk,
                             unsigned short* __restrict__ W_pk,
                             float* __restrict__ biasb) {
    __shared__ float lds_f[128 * LDSW];

    const int tid = threadIdx.x;
    const int t   = blockIdx.x;

    int gt = t * 256 + tid;
    if (gt < 2304) {
        biasb[gt] = (gt < 768) ? bq[gt] : (gt < 1536) ? bk[gt - 768] : bv[gt - 1536];
    }

    const float* src;
    unsigned short* dst;
    if (t < A_TILES) {
        const int mt = t / 12, kt = t - mt * 12;
        src = A + (size_t)mt * 128 * K_TOT + kt * 64;
        dst = A_pk + (size_t)t * TILE_ELEMS;
    } else {
        const int t2 = t - A_TILES;
        const int nt = t2 / 12, kt = t2 - nt * 12;
        const int which = nt / 6;
        const int row0  = (nt - which * 6) * 128;
        const float* w = (which == 0) ? wq : (which == 1) ? wk : wv;
        src = w + (size_t)row0 * K_TOT + kt * 64;
        dst = W_pk + (size_t)t2 * TILE_ELEMS;
    }

    #pragma unroll
    for (int j = 0; j < 8; ++j) {
        int f = j * 256 + tid;
        int row = f >> 4, c4 = f & 15;
        float4 v = *reinterpret_cast<const float4*>(src + (size_t)row * K_TOT + c4 * 4);
        *reinterpret_cast<float4*>(&lds_f[row * LDSW + c4 * 4]) = v;
    }
    __syncthreads();

    #pragma unroll
    for (int j = 0; j < 4; ++j) {
        int c = j * 256 + tid;
        int kb = c >> 7, row = c & 127;
        const float* p = &lds_f[row * LDSW + kb * 8];
        u16x8 o;
        #pragma unroll
        for (int e = 0; e < 8; ++e) o[e] = f2bf_rne(p[e]);
        *reinterpret_cast<u16x8*>(dst + (size_t)c * 8) = o;
    }
}

// ---------------------------------------------------------------------------
// Pass 2 (R12 champion, GEMM ~130us = m97-structure ceiling ~892 TF eff):
//   128x128 BK=64 compiler-scheduled 2-barrier GEMM; packed conflict-free
//   LDS [kb][row][8]; gld_lds16 staging; swapped-operand MFMA (lane's 4 acc
//   regs = 4 consecutive n); C-epilogue bounces through LDS and issues
//   FULLY-COALESCED nt stores (512B per 32 lanes, 128B-aligned -> no RMW;
//   C bypasses L2/L3 so A_pk/W_pk stay L3-resident -> staging = L3 hits).
//   __launch_bounds__(256,4): VGPR cap 128 fits acc[4][4]+frags (~90).
//   (256,5)/(512,4) cap below accumulator size -> scratch spill (R13/R17).
// ---------------------------------------------------------------------------
__global__ __launch_bounds__(256, 4) void qkv_gemm(
        const unsigned short* __restrict__ A_pk,
        const unsigned short* __restrict__ W_pk,
        const float* __restrict__ bias,
        float* __restrict__ out) {

    // overlay: main loop uses 32KB (sA 16KB + sB 16KB); epilogue reuses the
    // same memory as a 64x132 f32 staging tile (33792 B).
    __shared__ __align__(16) unsigned char smem[64 * 132 * 4];
    unsigned short* sA = (unsigned short*)smem;
    unsigned short* sB = (unsigned short*)(smem + 16384);
    float* sC = (float*)smem;

    const int tid  = threadIdx.x;
    const int lane = tid & 63;
    const int wid  = tid >> 6;
    const int wr   = wid >> 1;       // 0..1 : rows wr*64..+63
    const int wc   = wid & 1;        // 0..1 : cols wc*64..+63

    int bid = (int)blockIdx.x;
    bid = (bid & 7) * (NBLK / 8) + (bid >> 3);     // XCD-aware (bijective)
    const int bm = bid / NBN;
    const int bn = bid - bm * NBN;
    const int m0 = bm * BM;
    const int n0 = bn * BN;

    f32x4 acc[4][4];
    #pragma unroll
    for (int i = 0; i < 4; i++)
        #pragma unroll
        for (int j = 0; j < 4; j++)
            acc[i][j] = (f32x4){0.f, 0.f, 0.f, 0.f};

    const unsigned short* aT = A_pk + (size_t)bm * NKT * TILE_ELEMS;
    const unsigned short* bT = W_pk + (size_t)bn * NKT * TILE_ELEMS;

    // fragment read offsets (bytes) in packed LDS [kb][row][8]
    const int aBase = (((lane >> 4) << 10) + (wr * 64 + (lane & 15)) * 8) * 2;
    const int bBase = (((lane >> 4) << 10) + (wc * 64 + (lane & 15)) * 8) * 2;

    for (int kt = 0; kt < NKT; ++kt) {
        if (kt) __syncthreads();
        const unsigned short* aS = aT + kt * TILE_ELEMS;
        const unsigned short* bS = bT + kt * TILE_ELEMS;
        #pragma unroll
        for (int i = 0; i < 4; i++) {
            const int c = i * 256 + tid;
            gld_lds16(aS + c * 8, &sA[c * 8]);
            gld_lds16(bS + c * 8, &sB[c * 8]);
        }
        __syncthreads();

        #pragma unroll
        for (int kk = 0; kk < 2; kk++) {
            bf16x8 af[4], bf[4];
            #pragma unroll
            for (int i = 0; i < 4; i++)
                af[i] = *reinterpret_cast<const bf16x8*>(
                    (const char*)sA + aBase + i * 256 + kk * 8192);
            #pragma unroll
            for (int j = 0; j < 4; j++)
                bf[j] = *reinterpret_cast<const bf16x8*>(
                    (const char*)sB + bBase + j * 256 + kk * 8192);
            #pragma unroll
            for (int i = 0; i < 4; i++)
                #pragma unroll
                for (int j = 0; j < 4; j++)
                    // swapped operands: lane's 4 acc regs = 4 consecutive n
                    acc[i][j] = __builtin_amdgcn_mfma_f32_16x16x32_bf16(
                        bf[j], af[i], acc[i][j], 0, 0, 0);
        }
    }

    // ---- epilogue: LDS transpose-stage (2 halves of 2 i-stripes each), then
    // coalesced 512B-per-32-lane nt stores (128B-aligned, no RMW).
    const int which = n0 / H;
    const int c0    = n0 - which * H;
    float* outB = out + (size_t)which * OUT_PER + (size_t)m0 * H + c0;

    #pragma unroll
    for (int half = 0; half < 2; ++half) {
        __syncthreads();   // LDS free (main loop reads / prev half stores done)
        #pragma unroll
        for (int il = 0; il < 2; ++il) {
            const int i    = half * 2 + il;
            const int wrow = wr * 32 + il * 16 + (lane & 15);
            #pragma unroll
            for (int j = 0; j < 4; ++j) {
                const int col = wc * 64 + j * 16 + ((lane >> 4) << 2);
                const float4 bv4 = *reinterpret_cast<const float4*>(&bias[n0 + col]);
                f32x4 o;
                o[0] = acc[i][j][0] + bv4.x;
                o[1] = acc[i][j][1] + bv4.y;
                o[2] = acc[i][j][2] + bv4.z;
                o[3] = acc[i][j][3] + bv4.w;
                *reinterpret_cast<f32x4*>(&sC[wrow * 132 + col]) = o;
            }
        }
        __syncthreads();
        // read back + nt store: flat = row*32 + chunk; 32 lanes cover one full
        // 512B row segment -> perfectly coalesced, 128B-aligned.
        #pragma unroll
        for (int v = 0; v < 8; ++v) {
            const int flat  = v * 256 + tid;
            const int row   = flat >> 5;       // 0..63 (LDS row)
            const int chunk = flat & 31;       // 16B chunk in row
            f32x4 o = *reinterpret_cast<const f32x4*>(&sC[row * 132 + chunk * 4]);
            // LDS row -> global row: wr=row>>5, low5=row&31 (il*16+rr)
            const int grow = ((row >> 5) << 6) + half * 32 + (row & 31);
            __builtin_nontemporal_store(o,
                reinterpret_cast<f32x4*>(&outB[(size_t)grow * H + chunk * 4]));
        }
    }
}

extern "C" void kernel_launch(void* const* d_in, const int* in_sizes, int n_in,
                              void* d_out, int out_size, void* d_ws, size_t ws_size,
                              hipStream_t stream) {
    const float* hs = (const float*)d_in[0];
    const float* wq = (const float*)d_in[1];
    const float* bq = (const float*)d_in[2];
    const float* wk = (const float*)d_in[3];
    const float* bk = (const float*)d_in[4];
    const float* wv = (const float*)d_in[5];
    const float* bv = (const float*)d_in[6];

    unsigned short* A_pk = (unsigned short*)d_ws;                 // 50,331,648 B
    unsigned short* W_pk = A_pk + (size_t)A_TILES * TILE_ELEMS;   //  3,538,944 B
    float* biasb         = (float*)(W_pk + (size_t)W_TILES * TILE_ELEMS);

    hipLaunchKernelGGL(convert_pack, dim3(A_TILES + W_TILES), dim3(256), 0, stream,
                       hs, wq, wk, wv, bq, bk, bv, A_pk, W_pk, biasb);

    hipLaunchKernelGGL(qkv_gemm, dim3(NBLK), dim3(256), 0, stream,
                       A_pk, W_pk, biasb, (float*)d_out);
}